// Round 1
// baseline (111.113 us; speedup 1.0000x reference)
//
#include <hip/hip_runtime.h>

#define H 512
#define W 512
#define NIMG 8
#define SW 513                    // SAT dimension (H+1 = W+1)
#define SAT_PER (SW * SW)         // doubles per image-map SAT

// ---- helpers -------------------------------------------------------------

__device__ __forceinline__ float ldz(const float* __restrict__ p, int y, int x) {
    // zero-padded load ('SAME' conv padding)
    return ((unsigned)y < (unsigned)H && (unsigned)x < (unsigned)W) ? p[y * W + x] : 0.0f;
}

// Sobel (XLA conv = cross-correlation, no kernel flip):
// gx = (a02-a00) + 2(a12-a10) + (a22-a20)
// gy = (a20-a00) + 2(a21-a01) + (a22-a02)
__device__ __forceinline__ void sobel(const float* __restrict__ p, int y, int x,
                                      float& gx, float& gy) {
    float a00 = ldz(p, y - 1, x - 1), a01 = ldz(p, y - 1, x), a02 = ldz(p, y - 1, x + 1);
    float a10 = ldz(p, y,     x - 1),                          a12 = ldz(p, y,     x + 1);
    float a20 = ldz(p, y + 1, x - 1), a21 = ldz(p, y + 1, x), a22 = ldz(p, y + 1, x + 1);
    gx = (a02 - a00) + 2.0f * (a12 - a10) + (a22 - a20);
    gy = (a20 - a00) + 2.0f * (a21 - a01) + (a22 - a02);
}

// ---- kernel 1: per-row gradient energy + row-inclusive prefix (f64) ------
// SAT layout: sat[(n*2+m)*SAT_PER + y*SW + x], exclusive SAT:
//   S[y][x] = sum of E[y'][x'] for y'<y, x'<x.
// Row pass writes R[y+1][x+1] = prefix_x(E[y][:]) and R[y+1][0] = 0.
__global__ __launch_bounds__(512) void k_rowpass(const float* __restrict__ v,
                                                 const float* __restrict__ i_,
                                                 double* __restrict__ sat) {
    const int x = threadIdx.x;   // 0..511
    const int y = blockIdx.x;    // 0..511
    const int n = blockIdx.y;    // image
    const int m = blockIdx.z;    // 0 -> v, 1 -> i
    const float* src = (m == 0 ? v : i_) + (size_t)n * (H * W);

    float gx, gy;
    sobel(src, y, x, gx, gy);
    double e = (double)(gx * gx + gy * gy);

    __shared__ double s[512];
    s[x] = e;
    __syncthreads();
    // Hillis-Steele inclusive scan over 512 (f64)
    #pragma unroll
    for (int off = 1; off < 512; off <<= 1) {
        double t = (x >= off) ? s[x - off] : 0.0;
        __syncthreads();
        s[x] += t;
        __syncthreads();
    }
    double* row = sat + ((size_t)(n * 2 + m) * SAT_PER) + (size_t)(y + 1) * SW;
    row[x + 1] = s[x];
    if (x == 0) row[0] = 0.0;
}

// ---- kernel 2: column running sum (in place) -----------------------------
__global__ __launch_bounds__(64) void k_colpass(double* __restrict__ sat) {
    const int x = blockIdx.x * 64 + threadIdx.x;
    if (x >= SW) return;
    double* base = sat + (size_t)(blockIdx.y * 2 + blockIdx.z) * SAT_PER;
    base[x] = 0.0;  // SAT row 0 = zeros
    double run = 0.0;
    for (int y = 1; y < SW; ++y) {
        run += base[(size_t)y * SW + x];
        base[(size_t)y * SW + x] = run;
    }
}

// ---- kernel 3: fused Sobel + 5-window weighted residual ------------------
__global__ __launch_bounds__(256) void k_main(const float* __restrict__ v,
                                              const float* __restrict__ i_,
                                              const float* __restrict__ img,
                                              const double* __restrict__ sat,
                                              double* __restrict__ partials) {
    const int x = blockIdx.x * 64 + threadIdx.x;   // blockDim = (64,4)
    const int y = blockIdx.y * 4 + threadIdx.y;
    const int n = blockIdx.z;
    const float* pv = v   + (size_t)n * (H * W);
    const float* pi = i_  + (size_t)n * (H * W);
    const float* pf = img + (size_t)n * (H * W);

    float gvx, gvy, gix, giy, gfx, gfy;
    sobel(pv, y, x, gvx, gvy);
    sobel(pi, y, x, gix, giy);
    sobel(pf, y, x, gfx, gfy);

    const double* Sv = sat + (size_t)(n * 2 + 0) * SAT_PER;
    const double* Si = sat + (size_t)(n * 2 + 1) * SAT_PER;

    const int   radii[5] = {1, 3, 7, 15, 30};
    const double iw2[5]  = {1.0 / 9.0, 1.0 / 49.0, 1.0 / 225.0, 1.0 / 961.0, 1.0 / 3721.0};

    float acc = 0.0f;
    #pragma unroll
    for (int k = 0; k < 5; ++k) {
        const int r  = radii[k];
        const int y0 = max(y - r, 0), y1 = min(y + r + 1, H);
        const int x0 = max(x - r, 0), x1 = min(x + r + 1, W);
        double sv = Sv[(size_t)y1 * SW + x1] - Sv[(size_t)y0 * SW + x1]
                  - Sv[(size_t)y1 * SW + x0] + Sv[(size_t)y0 * SW + x0];
        double si = Si[(size_t)y1 * SW + x1] - Si[(size_t)y0 * SW + x1]
                  - Si[(size_t)y1 * SW + x0] + Si[(size_t)y0 * SW + x0];
        float ev = (float)(sv * iw2[k]);
        float ei = (float)(si * iw2[k]);
        float wt = ev / (ev + ei + 1e-8f);
        float tx = gix + wt * (gvx - gix);   // wt*gvx + (1-wt)*gix
        float ty = giy + wt * (gvy - giy);
        float dx = gfx - tx, dy = gfy - ty;
        acc += dx * dx + dy * dy;
    }

    // block reduction (f64), deterministic
    __shared__ double red[256];
    const int tid = threadIdx.y * 64 + threadIdx.x;
    red[tid] = (double)acc;
    __syncthreads();
    #pragma unroll
    for (int s = 128; s > 0; s >>= 1) {
        if (tid < s) red[tid] += red[tid + s];
        __syncthreads();
    }
    if (tid == 0) {
        const int bid = (blockIdx.z * gridDim.y + blockIdx.y) * gridDim.x + blockIdx.x;
        partials[bid] = red[0];
    }
}

// ---- kernel 4: final reduce ----------------------------------------------
__global__ __launch_bounds__(256) void k_reduce(const double* __restrict__ partials,
                                                int np, float* __restrict__ out) {
    __shared__ double red[256];
    double s = 0.0;
    for (int idx = threadIdx.x; idx < np; idx += 256) s += partials[idx];
    red[threadIdx.x] = s;
    __syncthreads();
    #pragma unroll
    for (int t = 128; t > 0; t >>= 1) {
        if (threadIdx.x < t) red[threadIdx.x] += red[threadIdx.x + t];
        __syncthreads();
    }
    if (threadIdx.x == 0)
        out[0] = (float)(red[0] / (double)((size_t)NIMG * H * W));
}

// ---- launch --------------------------------------------------------------

extern "C" void kernel_launch(void* const* d_in, const int* in_sizes, int n_in,
                              void* d_out, int out_size, void* d_ws, size_t ws_size,
                              hipStream_t stream) {
    const float* v   = (const float*)d_in[0];
    const float* i_  = (const float*)d_in[1];
    const float* img = (const float*)d_in[2];
    float* out = (float*)d_out;

    double* sat      = (double*)d_ws;                         // 16 * 513*513 f64 = 33,685,632 B
    double* partials = sat + (size_t)16 * SAT_PER;            // 8192 f64
    const int nblocks = 8 * 128 * NIMG;                       // k_main grid size

    k_rowpass<<<dim3(512, NIMG, 2), dim3(512), 0, stream>>>(v, i_, sat);
    k_colpass<<<dim3((SW + 63) / 64, NIMG, 2), dim3(64), 0, stream>>>(sat);
    k_main<<<dim3(W / 64, H / 4, NIMG), dim3(64, 4), 0, stream>>>(v, i_, img, sat, partials);
    k_reduce<<<dim3(1), dim3(256), 0, stream>>>(partials, nblocks, out);
}